// Round 13
// baseline (212.367 us; speedup 1.0000x reference)
//
#include <hip/hip_runtime.h>

// ResGCNBlock: out = LN(relu(scatter_add(norm * (xW^T+b)[row] -> col))) + x
// N=50000, D=128, E=800000, fp32.
// Round 23: fold k_scan INTO the k_gemm_hist launch. r22 proved a boundary
//   is worth ~3-4us (lookback merge gained 3.6). Now 49 scan-role blocks
//   (1024 thr, 1024 nodes each) ride in the gemm_hist grid: spin on a
//   device-scope done-counter until all 2K hist blocks publish
//   (threadfence + atomicAdd release), then run the r22 lookback scan
//   (sid<=48 -> single 64-lane pass). partial[]+done zeroed by a 1KB
//   hipMemsetAsync BEFORE the launch (in-kernel zeroing would race with
//   same-kernel publishes). Deadlock-free: 295 blocks @1024thr < 512
//   co-residency; hist/GEMM never wait. Dispatches 4 -> 3 (+tiny memset).
//   History: global atomics dead on gfx950 (r4/r7) -> LDS histograms (r8);
//   __shfl from inactive lanes UNDEFINED -> wave-uniform trips (r10);
//   4-wide load groups (r12); k_agg ILP/TLP variants all regressed
//   (r13-r18) -> r12 structure is the gather floor; pre8 u8 + srcs u16
//   (r20); cooperative grid.sync ~100us+/sync on gfx950 (r21, 3x worse);
//   lookback scan merge (r22, best=173.4).

#define D 128
#define CHSH 15                      // chunk = 32768 edges per hist block
#define CHUNK (1 << CHSH)
#define NWORD 12500                  // ceil(50000/4) packed-byte LDS words

typedef short bf16x8 __attribute__((ext_vector_type(8)));
typedef float f32x4 __attribute__((ext_vector_type(4)));

__device__ __forceinline__ unsigned short f2bf(float f) {
    unsigned u = __float_as_uint(f);
    return (unsigned short)((u + 0x7fffu + ((u >> 16) & 1u)) >> 16);
}
__device__ __forceinline__ float bf2f_lo(unsigned v) { return __uint_as_float(v << 16); }
__device__ __forceinline__ float bf2f_hi(unsigned v) { return __uint_as_float(v & 0xffff0000u); }

// ---------- merged (1024-thr): hist [0,2K) + GEMM + lookback-scan tail ----------
// hist block: work -> threadfence -> atomicAdd(done). scan block: spin on
// done==2K -> threadfence -> dis/pre8/rowptr with decoupled lookback.
__global__ void __launch_bounds__(1024)
k_gemm_hist(const float* __restrict__ x, const float* __restrict__ W,
            const float* __restrict__ bias, unsigned short* __restrict__ hb,
            int nrows,
            const int* __restrict__ ei, int E, int n,
            unsigned char* __restrict__ degc, unsigned char* __restrict__ cntc,
            unsigned char* __restrict__ aux,
            float* __restrict__ dis, int* __restrict__ rowptr,
            unsigned char* __restrict__ pre8,
            unsigned* __restrict__ partial, unsigned* __restrict__ done,
            int K, int gemm_blocks) {
    __shared__ unsigned sm[NWORD];                 // 50 KB: hist / W-frag / scan ps
    int bid = blockIdx.x;
    int t = threadIdx.x;
    if (bid < 2 * K) {
        // ---- hist role ----
        unsigned* hist = sm;
        bool is_cnt = bid < K;
        int c = is_cnt ? bid : bid - K;
        const int* vs = is_cnt ? (ei + E) : ei;    // dest for cnt, source for deg
        for (int i = t; i < NWORD; i += 1024) hist[i] = 0u;
        __syncthreads();
        int e0 = c << CHSH;
        int e1 = e0 + CHUNK; if (e1 > E) e1 = E;
        if (is_cnt) {
            for (int e = e0 + t; e < e1; e += 1024) {
                int v = vs[e];
                unsigned sh = (v & 3) * 8;
                unsigned old = atomicAdd(&hist[v >> 2], 1u << sh);
                aux[e] = (unsigned char)(old >> sh);   // rank within (chunk, dest)
            }
        } else {
            for (int e = e0 + t; e < e1; e += 1024) {
                int v = vs[e];
                atomicAdd(&hist[v >> 2], 1u << ((v & 3) * 8));
            }
        }
        __syncthreads();
        unsigned* dst = (unsigned*)((is_cnt ? cntc : degc) + (size_t)c * n);
        for (int i = t; i < NWORD; i += 1024) dst[i] = hist[i];
        // release: my stores -> fence (every thread) -> barrier -> counter
        __threadfence();
        __syncthreads();
        if (t == 0) atomicAdd(done, 1u);
    } else if (bid < 2 * K + gemm_blocks) {
        // ---- GEMM role: 16 waves, 256 rows per block ----
        unsigned short* wf = (unsigned short*)sm;
        for (int s = t; s < D * D; s += 1024) {
            int j  = s & 7;
            int ln = (s >> 3) & 63;
            int g  = s >> 9;                       // nt*4 + kt
            int kt = g & 3, nt = g >> 2;
            int rw = nt * 16 + (ln & 15);
            int cl = kt * 32 + (ln >> 4) * 8 + j;
            wf[s] = f2bf(W[rw * D + cl]);
        }
        __syncthreads();

        int wid = t >> 6, lane = t & 63;
        int m0 = (bid - 2 * K) * 256 + wid * 16;
        if (m0 >= nrows) return;
        int lo16 = lane & 15, quad = lane >> 4;
        const float* arow = x + (size_t)(m0 + lo16) * D + quad * 8;
        bf16x8 a[4];
        #pragma unroll
        for (int kt = 0; kt < 4; kt++) {
            float4 p = *(const float4*)(arow + kt * 32);
            float4 q = *(const float4*)(arow + kt * 32 + 4);
            bf16x8 av;
            av[0] = (short)f2bf(p.x); av[1] = (short)f2bf(p.y);
            av[2] = (short)f2bf(p.z); av[3] = (short)f2bf(p.w);
            av[4] = (short)f2bf(q.x); av[5] = (short)f2bf(q.y);
            av[6] = (short)f2bf(q.z); av[7] = (short)f2bf(q.w);
            a[kt] = av;
        }
        const bf16x8* wfv = (const bf16x8*)sm;
        #pragma unroll
        for (int nt = 0; nt < 8; nt++) {
            int n0 = nt * 16;
            float bj = bias[n0 + lo16];
            f32x4 acc = {bj, bj, bj, bj};
            #pragma unroll
            for (int kt = 0; kt < 4; kt++) {
                bf16x8 b = wfv[(nt * 4 + kt) * 64 + lane];
                acc = __builtin_amdgcn_mfma_f32_16x16x32_bf16(a[kt], b, acc, 0, 0, 0);
            }
            #pragma unroll
            for (int r = 0; r < 4; r++) {
                int gr = m0 + quad * 4 + r;
                hb[(size_t)gr * D + n0 + lo16] = f2bf(acc[r]);
            }
        }
    } else {
        // ---- scan role: sid covers nodes sid*1024 + t ----
        int sid = bid - 2 * K - gemm_blocks;
        __shared__ unsigned bb_sh;
        // acquire: wait for all hist blocks
        if (t == 0) {
            while (atomicAdd(done, 0u) < 2u * (unsigned)K) {}
        }
        __syncthreads();
        __threadfence();
        int i = sid * 1024 + t;
        unsigned tot = 0;
        if (i < n) {
            unsigned d = 0;
            for (int c = 0; c < K; c++)
                d += __builtin_nontemporal_load(degc + (size_t)c * n + i);
            dis[i] = rsqrtf((float)d + 1.0f);      // +1 = self loop
            unsigned run = 0;                      // run <= row degree << 255
            for (int c = 0; c < K; c++) {
                pre8[(size_t)c * n + i] = (unsigned char)run;
                run += cntc[(size_t)c * n + i];
            }
            tot = run;
        }
        // inclusive 1024-wide block scan
        sm[t] = tot;
        __syncthreads();
        for (int d = 1; d < 1024; d <<= 1) {
            unsigned u = (t >= d) ? sm[t - d] : 0u;
            __syncthreads();
            sm[t] += u;
            __syncthreads();
        }
        unsigned incl = sm[t];
        unsigned agg  = sm[1023];
        // lookback by wave 0 (sid <= 48 < 64: single pass)
        if (t < 64) {
            if (t == 0) atomicExch(&partial[sid], agg | 0x80000000u);
            unsigned sum = 0;
            if (t < sid) {
                unsigned v;
                do { v = atomicAdd(&partial[t], 0u); } while (!(v & 0x80000000u));
                sum = v & 0x7fffffffu;
            }
            #pragma unroll
            for (int mm = 32; mm >= 1; mm >>= 1) sum += __shfl_xor(sum, mm, 64);
            if (t == 0) bb_sh = sum;
        }
        __syncthreads();
        unsigned bbase = bb_sh;
        if (i < n) rowptr[i] = (int)(bbase + incl - tot);
        if (sid == 0 && t == 0) rowptr[n] = E;
    }
}

// ---------- atomic-free bucket fill using (copy = e>>CHSH, rank = aux[e]) ----------
// srcs stored as u16 (N = 50000 < 65536).
__global__ void k_fill(const int* __restrict__ ei, int E, int n,
                       const int* __restrict__ rowptr, const unsigned char* __restrict__ pre8,
                       const unsigned char* __restrict__ aux,
                       unsigned short* __restrict__ srcs) {
    int e = blockIdx.x * 256 + threadIdx.x;
    if (e < E) {
        int r = __builtin_nontemporal_load(ei + e);          // read-once
        int v = __builtin_nontemporal_load(ei + E + e);      // read-once
        int c = e >> CHSH;
        int rank = __builtin_nontemporal_load(aux + e);      // read-once
        int base = rowptr[v] + (int)pre8[(size_t)c * n + v]; // hot 200KB + 1.25MB
        srcs[base + rank] = (unsigned short)r;               // 2B scatter
    }
}

// ---------- fused gather-aggregate + self-loop + relu + LN + residual ----------
// r12's proven structure: one wave per dest row; quad q (16 lanes) handles
// edges j==q (mod 4); lane t owns cols 8t..8t+7 (16B uint4 of bf16 per
// edge). 4-wide load groups: issue 4 independent gathers per quad, then
// consume. Group count wave-uniform; all shuffles full-wave (inactive-lane
// shuffle UNDEFINED on gfx950); pad lanes carry sv=0/dv=0 and self-mask.
__global__ void k_agg(const float* __restrict__ x, const unsigned short* __restrict__ hb,
                      const float* __restrict__ dis,
                      const int* __restrict__ rowptr, const unsigned short* __restrict__ srcs,
                      const float* __restrict__ gamma, const float* __restrict__ beta,
                      float* __restrict__ out, int n) {
    int wid = threadIdx.x >> 6, lane = threadIdx.x & 63;
    int row = blockIdx.x * 4 + wid;
    if (row >= n) return;
    int q = lane >> 4, t = lane & 15;
    float dc = dis[row];
    float acc[8];
    #pragma unroll
    for (int i = 0; i < 8; i++) acc[i] = 0.0f;
    if (q == 0) {                                     // self-loop: dis^2 * h[row]
        uint4 u = ((const uint4*)(hb + (size_t)row * D))[t];
        float sn = dc * dc;
        acc[0] = sn * bf2f_lo(u.x); acc[1] = sn * bf2f_hi(u.x);
        acc[2] = sn * bf2f_lo(u.y); acc[3] = sn * bf2f_hi(u.y);
        acc[4] = sn * bf2f_lo(u.z); acc[5] = sn * bf2f_hi(u.z);
        acc[6] = sn * bf2f_lo(u.w); acc[7] = sn * bf2f_hi(u.w);
    }
    int s0 = rowptr[row];
    int len = rowptr[row + 1] - s0;
    for (int base = 0; base < len; base += 64) {
        int idx = base + lane;
        int sv = (idx < len) ? (int)__builtin_nontemporal_load(srcs + s0 + idx) : 0;
        float dv = (idx < len) ? dis[sv] : 0.0f;      // pad: weight 0 (self-masks)
        int m = len - base; if (m > 64) m = 64;
        int kmax = (m + 3) >> 2;                      // 1..16, wave-uniform
        int gcount = (kmax + 3) >> 2;                 // 1..4 groups of 4 edges/quad
        for (int gg = 0; gg < gcount; gg++) {         // wave-uniform trip count
            int jb = q + (gg << 4);                   // jb+12 <= 63
            int r0 = __shfl(sv, jb, 64);
            int r1 = __shfl(sv, jb + 4, 64);
            int r2 = __shfl(sv, jb + 8, 64);
            int r3 = __shfl(sv, jb + 12, 64);
            float w0 = dc * __shfl(dv, jb, 64);       // 0 for stages >= m
            float w1 = dc * __shfl(dv, jb + 4, 64);
            float w2 = dc * __shfl(dv, jb + 8, 64);
            float w3 = dc * __shfl(dv, jb + 12, 64);
            // 4 independent gathers in flight before any consume
            uint4 u0 = ((const uint4*)(hb + ((size_t)r0 << 7)))[t];
            uint4 u1 = ((const uint4*)(hb + ((size_t)r1 << 7)))[t];
            uint4 u2 = ((const uint4*)(hb + ((size_t)r2 << 7)))[t];
            uint4 u3 = ((const uint4*)(hb + ((size_t)r3 << 7)))[t];
            acc[0] += w0 * bf2f_lo(u0.x); acc[1] += w0 * bf2f_hi(u0.x);
            acc[2] += w0 * bf2f_lo(u0.y); acc[3] += w0 * bf2f_hi(u0.y);
            acc[4] += w0 * bf2f_lo(u0.z); acc[5] += w0 * bf2f_hi(u0.z);
            acc[6] += w0 * bf2f_lo(u0.w); acc[7] += w0 * bf2f_hi(u0.w);
            acc[0] += w1 * bf2f_lo(u1.x); acc[1] += w1 * bf2f_hi(u1.x);
            acc[2] += w1 * bf2f_lo(u1.y); acc[3] += w1 * bf2f_hi(u1.y);
            acc[4] += w1 * bf2f_lo(u1.z); acc[5] += w1 * bf2f_hi(u1.z);
            acc[6] += w1 * bf2f_lo(u1.w); acc[7] += w1 * bf2f_hi(u1.w);
            acc[0] += w2 * bf2f_lo(u2.x); acc[1] += w2 * bf2f_hi(u2.x);
            acc[2] += w2 * bf2f_lo(u2.y); acc[3] += w2 * bf2f_hi(u2.y);
            acc[4] += w2 * bf2f_lo(u2.z); acc[5] += w2 * bf2f_hi(u2.z);
            acc[6] += w2 * bf2f_lo(u2.w); acc[7] += w2 * bf2f_hi(u2.w);
            acc[0] += w3 * bf2f_lo(u3.x); acc[1] += w3 * bf2f_hi(u3.x);
            acc[2] += w3 * bf2f_lo(u3.y); acc[3] += w3 * bf2f_hi(u3.y);
            acc[4] += w3 * bf2f_lo(u3.z); acc[5] += w3 * bf2f_hi(u3.z);
            acc[6] += w3 * bf2f_lo(u3.w); acc[7] += w3 * bf2f_hi(u3.w);
        }
    }
    // combine the 4 quads' partials (lanes t, t+16, t+32, t+48), then relu
    #pragma unroll
    for (int i = 0; i < 8; i++) {
        acc[i] += __shfl_xor(acc[i], 16, 64);
        acc[i] += __shfl_xor(acc[i], 32, 64);
        acc[i] = acc[i] > 0.0f ? acc[i] : 0.0f;
    }
    // LN over 128 cols: per-lane partial over its 8 cols, reduce across t
    float s1r = 0.0f, s2r = 0.0f;
    #pragma unroll
    for (int i = 0; i < 8; i++) { s1r += acc[i]; s2r += acc[i] * acc[i]; }
    #pragma unroll
    for (int mm = 8; mm >= 1; mm >>= 1) {
        s1r += __shfl_xor(s1r, mm, 64);
        s2r += __shfl_xor(s2r, mm, 64);
    }
    float mean = s1r * (1.0f / 128.0f);
    float var  = s2r * (1.0f / 128.0f) - mean * mean;  // population var (jnp.var)
    float rstd = rsqrtf(var + 1e-5f);
    if (q == 0) {                                      // 16 lanes store the row
        const f32x4* gr = (const f32x4*)gamma;
        const f32x4* br = (const f32x4*)beta;
        const f32x4* xr = (const f32x4*)(x + (size_t)row * D);
        f32x4* orow = (f32x4*)(out + (size_t)row * D);
        #pragma unroll
        for (int hf = 0; hf < 2; hf++) {
            f32x4 g = gr[2 * t + hf], b = br[2 * t + hf];
            f32x4 xx = __builtin_nontemporal_load(xr + 2 * t + hf);   // read-once
            f32x4 o;
            o[0] = (acc[4 * hf + 0] - mean) * rstd * g[0] + b[0] + xx[0];
            o[1] = (acc[4 * hf + 1] - mean) * rstd * g[1] + b[1] + xx[1];
            o[2] = (acc[4 * hf + 2] - mean) * rstd * g[2] + b[2] + xx[2];
            o[3] = (acc[4 * hf + 3] - mean) * rstd * g[3] + b[3] + xx[3];
            __builtin_nontemporal_store(o, orow + 2 * t + hf);        // write-once
        }
    }
}

extern "C" void kernel_launch(void* const* d_in, const int* in_sizes, int n_in,
                              void* d_out, int out_size, void* d_ws, size_t ws_size,
                              hipStream_t stream) {
    const float* x     = (const float*)d_in[0];
    const int*   ei    = (const int*)d_in[1];   // [2, E]
    const float* W     = (const float*)d_in[2];
    const float* bias  = (const float*)d_in[3];
    const float* gamma = (const float*)d_in[4];
    const float* beta  = (const float*)d_in[5];
    int N = in_sizes[0] / D;
    int E = in_sizes[1] / 2;
    int nbE = (E + 255) / 256;                   // 3125
    int K   = (E + CHUNK - 1) >> CHSH;           // 25 chunks / copies
    int gemm_blocks = (N + 255) / 256;           // 196 (256 rows per 1024-thr block)
    int nscan = (N + 1023) / 1024;               // 49 scan-role blocks (<= 64)

    char* ws = (char*)d_ws;
    size_t off = 0;
    unsigned short* hb  = (unsigned short*)(ws + off); off += (size_t)N * D * 2;       // 12.8 MB
    unsigned char* degc = (unsigned char*)(ws + off);  off += (size_t)K * N;           // 1.25 MB
    unsigned char* cntc = (unsigned char*)(ws + off);  off += (size_t)K * N;           // 1.25 MB
    float*    dis       = (float*)(ws + off);          off += (size_t)N * 4;
    int*      rowptr    = (int*)(ws + off);            off += (size_t)(N + 1) * 4;
    unsigned char* pre8 = (unsigned char*)(ws + off);  off += (size_t)K * N;           // 1.25 MB
    unsigned* partial   = (unsigned*)(ws + off);       off += 256 * 4;
    unsigned* done      = (unsigned*)(ws + off);       off += 64;                      // own line
    unsigned char* aux  = (unsigned char*)(ws + off);  off += (size_t)E;               // 0.8 MB
    off = (off + 1) & ~(size_t)1;
    unsigned short* srcs = (unsigned short*)(ws + off); off += (size_t)E * 2;          // 1.6 MB
    float*    out       = (float*)d_out;

    // zero the handshake state (partial[256] + done) before the merged launch
    hipMemsetAsync(partial, 0, 256 * 4 + 64, stream);

    k_gemm_hist<<<2 * K + gemm_blocks + nscan, 1024, 0, stream>>>(
        x, W, bias, hb, N, ei, E, N, degc, cntc, aux,
        dis, rowptr, pre8, partial, done, K, gemm_blocks);
    k_fill<<<nbE, 256, 0, stream>>>(ei, E, N, rowptr, pre8, aux, srcs);
    k_agg<<<(N + 3) / 4, 256, 0, stream>>>(x, hb, dis, rowptr, srcs, gamma, beta, out, N);
}

// Round 14
// 174.831 us; speedup vs baseline: 1.2147x; 1.2147x over previous
//
#include <hip/hip_runtime.h>

// ResGCNBlock: out = LN(relu(scatter_add(norm * (xW^T+b)[row] -> col))) + x
// N=50000, D=128, E=800000, fp32.
// Round 24 = exact revert to r22 (best=173.4). r23's in-kernel handshake
//   (spin on device atomic) cost ~70us: 49 pollers serialize the done-line,
//   hist releases queue behind them. RULE (measured r21+r23): cross-WG sync
//   inside a kernel on gfx950 costs 20-30x a kernel boundary (~3.6us, r22).
//   Remaining controllable slack ~11us (3 boundaries); both claim mechanisms
//   are measured net-negative. k_agg at its latency floor (r13-r18 bracket).
//   History: global atomics dead on gfx950 (r4/r7) -> LDS histograms (r8);
//   __shfl from inactive lanes UNDEFINED -> wave-uniform trips (r10);
//   NT streams (r11); 4-wide load groups (r12); premul srcs2 regressed
//   (r13-r15); dual-row ILP occ 67->41% regressed (r17); half-row TLP 2x
//   gather instrs regressed (r18); pre8 u8 + srcs u16 (r20); cooperative
//   grid.sync ~100us+ (r21); lookback scan merge +3.6us (r22, best).

#define D 128
#define CHSH 15                      // chunk = 32768 edges per hist block
#define CHUNK (1 << CHSH)
#define NWORD 12500                  // ceil(50000/4) packed-byte LDS words

typedef short bf16x8 __attribute__((ext_vector_type(8)));
typedef float f32x4 __attribute__((ext_vector_type(4)));

__device__ __forceinline__ unsigned short f2bf(float f) {
    unsigned u = __float_as_uint(f);
    return (unsigned short)((u + 0x7fffu + ((u >> 16) & 1u)) >> 16);
}
__device__ __forceinline__ float bf2f_lo(unsigned v) { return __uint_as_float(v << 16); }
__device__ __forceinline__ float bf2f_hi(unsigned v) { return __uint_as_float(v & 0xffff0000u); }

// ---------- merged (1024-thr): cnt-hist [0,K) + deg-hist [K,2K) + GEMM rest ----------
// block 0 additionally zeroes partial[] (consumed by k_scan, next dispatch).
__global__ void __launch_bounds__(1024)
k_gemm_hist(const float* __restrict__ x, const float* __restrict__ W,
            const float* __restrict__ bias, unsigned short* __restrict__ hb,
            int nrows,
            const int* __restrict__ ei, int E, int n,
            unsigned char* __restrict__ degc, unsigned char* __restrict__ cntc,
            unsigned char* __restrict__ aux, unsigned* __restrict__ partial, int K) {
    __shared__ unsigned sm[NWORD];                 // 50 KB: hist OR W-frag staging
    int bid = blockIdx.x;
    if (bid < 2 * K) {
        if (bid == 0 && threadIdx.x < 256) partial[threadIdx.x] = 0u;  // lookback flags
        unsigned* hist = sm;
        bool is_cnt = bid < K;
        int c = is_cnt ? bid : bid - K;
        const int* vs = is_cnt ? (ei + E) : ei;    // dest for cnt, source for deg
        for (int i = threadIdx.x; i < NWORD; i += 1024) hist[i] = 0u;
        __syncthreads();
        int e0 = c << CHSH;
        int e1 = e0 + CHUNK; if (e1 > E) e1 = E;
        if (is_cnt) {
            for (int e = e0 + threadIdx.x; e < e1; e += 1024) {
                int v = vs[e];
                unsigned sh = (v & 3) * 8;
                unsigned old = atomicAdd(&hist[v >> 2], 1u << sh);
                aux[e] = (unsigned char)(old >> sh);   // rank within (chunk, dest)
            }
        } else {
            for (int e = e0 + threadIdx.x; e < e1; e += 1024) {
                int v = vs[e];
                atomicAdd(&hist[v >> 2], 1u << ((v & 3) * 8));
            }
        }
        __syncthreads();
        unsigned* dst = (unsigned*)((is_cnt ? cntc : degc) + (size_t)c * n);
        for (int i = threadIdx.x; i < NWORD; i += 1024) dst[i] = hist[i];
    } else {
        // ---- GEMM role: 16 waves, 256 rows per block ----
        unsigned short* wf = (unsigned short*)sm;
        for (int s = threadIdx.x; s < D * D; s += 1024) {
            int j  = s & 7;
            int ln = (s >> 3) & 63;
            int g  = s >> 9;                       // nt*4 + kt
            int kt = g & 3, nt = g >> 2;
            int rw = nt * 16 + (ln & 15);
            int cl = kt * 32 + (ln >> 4) * 8 + j;
            wf[s] = f2bf(W[rw * D + cl]);
        }
        __syncthreads();

        int wid = threadIdx.x >> 6, lane = threadIdx.x & 63;
        int m0 = (bid - 2 * K) * 256 + wid * 16;
        if (m0 >= nrows) return;
        int lo16 = lane & 15, quad = lane >> 4;
        const float* arow = x + (size_t)(m0 + lo16) * D + quad * 8;
        bf16x8 a[4];
        #pragma unroll
        for (int kt = 0; kt < 4; kt++) {
            float4 p = *(const float4*)(arow + kt * 32);
            float4 q = *(const float4*)(arow + kt * 32 + 4);
            bf16x8 av;
            av[0] = (short)f2bf(p.x); av[1] = (short)f2bf(p.y);
            av[2] = (short)f2bf(p.z); av[3] = (short)f2bf(p.w);
            av[4] = (short)f2bf(q.x); av[5] = (short)f2bf(q.y);
            av[6] = (short)f2bf(q.z); av[7] = (short)f2bf(q.w);
            a[kt] = av;
        }
        const bf16x8* wfv = (const bf16x8*)sm;
        #pragma unroll
        for (int nt = 0; nt < 8; nt++) {
            int n0 = nt * 16;
            float bj = bias[n0 + lo16];
            f32x4 acc = {bj, bj, bj, bj};
            #pragma unroll
            for (int kt = 0; kt < 4; kt++) {
                bf16x8 b = wfv[(nt * 4 + kt) * 64 + lane];
                acc = __builtin_amdgcn_mfma_f32_16x16x32_bf16(a[kt], b, acc, 0, 0, 0);
            }
            #pragma unroll
            for (int r = 0; r < 4; r++) {
                int gr = m0 + quad * 4 + r;
                hb[(size_t)gr * D + n0 + lo16] = f2bf(acc[r]);
            }
        }
    }
}

// ---------- single-pass scan: dis + pre8 + rowptr via decoupled lookback ----------
// 196 blocks (all co-resident: no deadlock). Block publishes its aggregate
// with READY (bit31); waits for predecessors' aggregates; sums -> base.
__global__ void k_scan(const unsigned char* __restrict__ degc,
                       const unsigned char* __restrict__ cntc,
                       float* __restrict__ dis, int* __restrict__ rowptr,
                       unsigned char* __restrict__ pre8,
                       unsigned* __restrict__ partial, int n, int E, int K) {
    __shared__ unsigned ps[256];
    __shared__ unsigned bb_sh;
    int t = threadIdx.x, bid = blockIdx.x;
    int i = bid * 256 + t;
    unsigned tot = 0;
    if (i < n) {
        unsigned d = 0;
        for (int c = 0; c < K; c++)
            d += __builtin_nontemporal_load(degc + (size_t)c * n + i);  // read-once
        dis[i] = rsqrtf((float)d + 1.0f);          // +1 = self loop
        unsigned run = 0;                          // run <= row degree << 255
        for (int c = 0; c < K; c++) {
            pre8[(size_t)c * n + i] = (unsigned char)run;
            run += cntc[(size_t)c * n + i];        // single cntc pass (was 2)
        }
        tot = run;
    }
    // inclusive block scan of tot
    ps[t] = tot;
    __syncthreads();
    #pragma unroll
    for (int d = 1; d < 256; d <<= 1) {
        unsigned u = (t >= d) ? ps[t - d] : 0u;
        __syncthreads();
        ps[t] += u;
        __syncthreads();
    }
    unsigned incl = ps[t];
    unsigned agg  = ps[255];                       // block aggregate
    // wave 0: publish aggregate, then lookback-sum all predecessors
    if (t < 64) {
        if (t == 0) atomicExch(&partial[bid], agg | 0x80000000u);
        unsigned sum = 0;
        for (int j0 = 0; j0 < bid; j0 += 64) {
            int j = j0 + t;
            if (j < bid) {
                unsigned v;
                do { v = atomicAdd(&partial[j], 0u); } while (!(v & 0x80000000u));
                sum += v & 0x7fffffffu;
            }
        }
        #pragma unroll
        for (int mm = 32; mm >= 1; mm >>= 1) sum += __shfl_xor(sum, mm, 64);
        if (t == 0) bb_sh = sum;
    }
    __syncthreads();
    unsigned bbase = bb_sh;
    if (i < n) rowptr[i] = (int)(bbase + incl - tot);
    if (bid == 0 && t == 0) rowptr[n] = E;
}

// ---------- atomic-free bucket fill using (copy = e>>CHSH, rank = aux[e]) ----------
// srcs stored as u16 (N = 50000 < 65536).
__global__ void k_fill(const int* __restrict__ ei, int E, int n,
                       const int* __restrict__ rowptr, const unsigned char* __restrict__ pre8,
                       const unsigned char* __restrict__ aux,
                       unsigned short* __restrict__ srcs) {
    int e = blockIdx.x * 256 + threadIdx.x;
    if (e < E) {
        int r = __builtin_nontemporal_load(ei + e);          // read-once
        int v = __builtin_nontemporal_load(ei + E + e);      // read-once
        int c = e >> CHSH;
        int rank = __builtin_nontemporal_load(aux + e);      // read-once
        int base = rowptr[v] + (int)pre8[(size_t)c * n + v]; // hot 200KB + 1.25MB
        srcs[base + rank] = (unsigned short)r;               // 2B scatter
    }
}

// ---------- fused gather-aggregate + self-loop + relu + LN + residual ----------
// r12's proven structure: one wave per dest row; quad q (16 lanes) handles
// edges j==q (mod 4); lane t owns cols 8t..8t+7 (16B uint4 of bf16 per
// edge). 4-wide load groups: issue 4 independent gathers per quad, then
// consume. Group count wave-uniform; all shuffles full-wave (inactive-lane
// shuffle UNDEFINED on gfx950); pad lanes carry sv=0/dv=0 and self-mask.
__global__ void k_agg(const float* __restrict__ x, const unsigned short* __restrict__ hb,
                      const float* __restrict__ dis,
                      const int* __restrict__ rowptr, const unsigned short* __restrict__ srcs,
                      const float* __restrict__ gamma, const float* __restrict__ beta,
                      float* __restrict__ out, int n) {
    int wid = threadIdx.x >> 6, lane = threadIdx.x & 63;
    int row = blockIdx.x * 4 + wid;
    if (row >= n) return;
    int q = lane >> 4, t = lane & 15;
    float dc = dis[row];
    float acc[8];
    #pragma unroll
    for (int i = 0; i < 8; i++) acc[i] = 0.0f;
    if (q == 0) {                                     // self-loop: dis^2 * h[row]
        uint4 u = ((const uint4*)(hb + (size_t)row * D))[t];
        float sn = dc * dc;
        acc[0] = sn * bf2f_lo(u.x); acc[1] = sn * bf2f_hi(u.x);
        acc[2] = sn * bf2f_lo(u.y); acc[3] = sn * bf2f_hi(u.y);
        acc[4] = sn * bf2f_lo(u.z); acc[5] = sn * bf2f_hi(u.z);
        acc[6] = sn * bf2f_lo(u.w); acc[7] = sn * bf2f_hi(u.w);
    }
    int s0 = rowptr[row];
    int len = rowptr[row + 1] - s0;
    for (int base = 0; base < len; base += 64) {
        int idx = base + lane;
        int sv = (idx < len) ? (int)__builtin_nontemporal_load(srcs + s0 + idx) : 0;
        float dv = (idx < len) ? dis[sv] : 0.0f;      // pad: weight 0 (self-masks)
        int m = len - base; if (m > 64) m = 64;
        int kmax = (m + 3) >> 2;                      // 1..16, wave-uniform
        int gcount = (kmax + 3) >> 2;                 // 1..4 groups of 4 edges/quad
        for (int gg = 0; gg < gcount; gg++) {         // wave-uniform trip count
            int jb = q + (gg << 4);                   // jb+12 <= 63
            int r0 = __shfl(sv, jb, 64);
            int r1 = __shfl(sv, jb + 4, 64);
            int r2 = __shfl(sv, jb + 8, 64);
            int r3 = __shfl(sv, jb + 12, 64);
            float w0 = dc * __shfl(dv, jb, 64);       // 0 for stages >= m
            float w1 = dc * __shfl(dv, jb + 4, 64);
            float w2 = dc * __shfl(dv, jb + 8, 64);
            float w3 = dc * __shfl(dv, jb + 12, 64);
            // 4 independent gathers in flight before any consume
            uint4 u0 = ((const uint4*)(hb + ((size_t)r0 << 7)))[t];
            uint4 u1 = ((const uint4*)(hb + ((size_t)r1 << 7)))[t];
            uint4 u2 = ((const uint4*)(hb + ((size_t)r2 << 7)))[t];
            uint4 u3 = ((const uint4*)(hb + ((size_t)r3 << 7)))[t];
            acc[0] += w0 * bf2f_lo(u0.x); acc[1] += w0 * bf2f_hi(u0.x);
            acc[2] += w0 * bf2f_lo(u0.y); acc[3] += w0 * bf2f_hi(u0.y);
            acc[4] += w0 * bf2f_lo(u0.z); acc[5] += w0 * bf2f_hi(u0.z);
            acc[6] += w0 * bf2f_lo(u0.w); acc[7] += w0 * bf2f_hi(u0.w);
            acc[0] += w1 * bf2f_lo(u1.x); acc[1] += w1 * bf2f_hi(u1.x);
            acc[2] += w1 * bf2f_lo(u1.y); acc[3] += w1 * bf2f_hi(u1.y);
            acc[4] += w1 * bf2f_lo(u1.z); acc[5] += w1 * bf2f_hi(u1.z);
            acc[6] += w1 * bf2f_lo(u1.w); acc[7] += w1 * bf2f_hi(u1.w);
            acc[0] += w2 * bf2f_lo(u2.x); acc[1] += w2 * bf2f_hi(u2.x);
            acc[2] += w2 * bf2f_lo(u2.y); acc[3] += w2 * bf2f_hi(u2.y);
            acc[4] += w2 * bf2f_lo(u2.z); acc[5] += w2 * bf2f_hi(u2.z);
            acc[6] += w2 * bf2f_lo(u2.w); acc[7] += w2 * bf2f_hi(u2.w);
            acc[0] += w3 * bf2f_lo(u3.x); acc[1] += w3 * bf2f_hi(u3.x);
            acc[2] += w3 * bf2f_lo(u3.y); acc[3] += w3 * bf2f_hi(u3.y);
            acc[4] += w3 * bf2f_lo(u3.z); acc[5] += w3 * bf2f_hi(u3.z);
            acc[6] += w3 * bf2f_lo(u3.w); acc[7] += w3 * bf2f_hi(u3.w);
        }
    }
    // combine the 4 quads' partials (lanes t, t+16, t+32, t+48), then relu
    #pragma unroll
    for (int i = 0; i < 8; i++) {
        acc[i] += __shfl_xor(acc[i], 16, 64);
        acc[i] += __shfl_xor(acc[i], 32, 64);
        acc[i] = acc[i] > 0.0f ? acc[i] : 0.0f;
    }
    // LN over 128 cols: per-lane partial over its 8 cols, reduce across t
    float s1r = 0.0f, s2r = 0.0f;
    #pragma unroll
    for (int i = 0; i < 8; i++) { s1r += acc[i]; s2r += acc[i] * acc[i]; }
    #pragma unroll
    for (int mm = 8; mm >= 1; mm >>= 1) {
        s1r += __shfl_xor(s1r, mm, 64);
        s2r += __shfl_xor(s2r, mm, 64);
    }
    float mean = s1r * (1.0f / 128.0f);
    float var  = s2r * (1.0f / 128.0f) - mean * mean;  // population var (jnp.var)
    float rstd = rsqrtf(var + 1e-5f);
    if (q == 0) {                                      // 16 lanes store the row
        const f32x4* gr = (const f32x4*)gamma;
        const f32x4* br = (const f32x4*)beta;
        const f32x4* xr = (const f32x4*)(x + (size_t)row * D);
        f32x4* orow = (f32x4*)(out + (size_t)row * D);
        #pragma unroll
        for (int hf = 0; hf < 2; hf++) {
            f32x4 g = gr[2 * t + hf], b = br[2 * t + hf];
            f32x4 xx = __builtin_nontemporal_load(xr + 2 * t + hf);   // read-once
            f32x4 o;
            o[0] = (acc[4 * hf + 0] - mean) * rstd * g[0] + b[0] + xx[0];
            o[1] = (acc[4 * hf + 1] - mean) * rstd * g[1] + b[1] + xx[1];
            o[2] = (acc[4 * hf + 2] - mean) * rstd * g[2] + b[2] + xx[2];
            o[3] = (acc[4 * hf + 3] - mean) * rstd * g[3] + b[3] + xx[3];
            __builtin_nontemporal_store(o, orow + 2 * t + hf);        // write-once
        }
    }
}

extern "C" void kernel_launch(void* const* d_in, const int* in_sizes, int n_in,
                              void* d_out, int out_size, void* d_ws, size_t ws_size,
                              hipStream_t stream) {
    const float* x     = (const float*)d_in[0];
    const int*   ei    = (const int*)d_in[1];   // [2, E]
    const float* W     = (const float*)d_in[2];
    const float* bias  = (const float*)d_in[3];
    const float* gamma = (const float*)d_in[4];
    const float* beta  = (const float*)d_in[5];
    int N = in_sizes[0] / D;
    int E = in_sizes[1] / 2;
    int nb  = (N + 255) / 256;                   // 196 scan blocks (<=256)
    int nbE = (E + 255) / 256;                   // 3125
    int K   = (E + CHUNK - 1) >> CHSH;           // 25 chunks / copies
    int gemm_blocks = (N + 255) / 256;           // 196 (256 rows per 1024-thr block)

    char* ws = (char*)d_ws;
    size_t off = 0;
    unsigned short* hb  = (unsigned short*)(ws + off); off += (size_t)N * D * 2;       // 12.8 MB
    unsigned char* degc = (unsigned char*)(ws + off);  off += (size_t)K * N;           // 1.25 MB
    unsigned char* cntc = (unsigned char*)(ws + off);  off += (size_t)K * N;           // 1.25 MB
    float*    dis       = (float*)(ws + off);          off += (size_t)N * 4;
    int*      rowptr    = (int*)(ws + off);            off += (size_t)(N + 1) * 4;
    unsigned char* pre8 = (unsigned char*)(ws + off);  off += (size_t)K * N;           // 1.25 MB
    unsigned* partial   = (unsigned*)(ws + off);       off += 256 * 4;
    unsigned char* aux  = (unsigned char*)(ws + off);  off += (size_t)E;               // 0.8 MB
    off = (off + 1) & ~(size_t)1;
    unsigned short* srcs = (unsigned short*)(ws + off); off += (size_t)E * 2;          // 1.6 MB
    float*    out       = (float*)d_out;

    k_gemm_hist<<<2 * K + gemm_blocks, 1024, 0, stream>>>(x, W, bias, hb, N,
                                                          ei, E, N, degc, cntc, aux,
                                                          partial, K);
    k_scan<<<nb, 256, 0, stream>>>(degc, cntc, dis, rowptr, pre8, partial, N, E, K);
    k_fill<<<nbE, 256, 0, stream>>>(ei, E, N, rowptr, pre8, aux, srcs);
    k_agg<<<(N + 3) / 4, 256, 0, stream>>>(x, hb, dis, rowptr, srcs, gamma, beta, out, N);
}